// Round 1
// baseline (224.601 us; speedup 1.0000x reference)
//
#include <hip/hip_runtime.h>

#define V 16
#define MAXN 64
#define WAVES_PER_BLOCK 4

__device__ __forceinline__ float safe_(float d) { return (d == 0.0f) ? 1.0f : d; }

// One wave (64 lanes) per polygon pair. lane = vertex slot (MAXN==64).
__global__ __launch_bounds__(256) void poly_iou_kernel(
    const float* __restrict__ output,  // [B, 2V, HW]
    const float* __restrict__ mask,    // [B, K]
    const int*   __restrict__ ind,     // [B, K]
    const float* __restrict__ target,  // [B, K, 2V]
    float* __restrict__ acc,           // [2]: sum(iou*mask), sum(mask)
    int BK, int K, int HW)
{
    __shared__ float bufx[WAVES_PER_BLOCK][MAXN];
    __shared__ float bufy[WAVES_PER_BLOCK][MAXN];

    const int lane = threadIdx.x & 63;
    const int wave = threadIdx.x >> 6;
    int pair = blockIdx.x * WAVES_PER_BLOCK + wave;
    const bool live = pair < BK;
    if (!live) pair = 0;                 // keep wave running (uniform barriers)
    const int b = pair / K;

    // ---- load subject (pred, gathered) and clip (target) polygons ----
    float px = 0.0f, py = 0.0f;          // working poly[lane]
    float sx = 0.0f, sy = 0.0f;          // subject copy (for a_p)
    float cx = 0.0f, cy = 0.0f;          // clip vertex   (for edges + a_g)
    if (lane < V) {
        const int idx = ind[pair];
        const float* ob = output + ((size_t)b * (2 * V)) * (size_t)HW;
        sx = ob[(size_t)(2 * lane) * HW + idx];
        sy = ob[(size_t)(2 * lane + 1) * HW + idx];
        const float* tb = target + (size_t)pair * (2 * V);
        cx = tb[2 * lane];
        cy = tb[2 * lane + 1];
        px = sx; py = sy;
    }
    int n = V;

    // ---- Sutherland–Hodgman clip: 16 edges (c1=clip[t-1], c2=clip[t]) ----
    for (int t = 0; t < V; ++t) {
        const int t1 = (t + V - 1) & (V - 1);
        const float c1x = __shfl(cx, t1), c1y = __shfl(cy, t1);
        const float c2x = __shfl(cx, t),  c2y = __shfl(cy, t);

        const int ns = (n > 0) ? n : 1;
        const int pidx = (lane - 1 + ns) % ns;          // python (-1)%n semantics
        const float prx = __shfl(px, pidx);
        const float pry = __shfl(py, pidx);

        // inside test: R = (c2x-c1x)*(qy-c1y) - (c2y-c1y)*(qx-c1x); inside = R<=0
        const float Rc = (c2x - c1x) * (py - c1y) - (c2y - c1y) * (px - c1x);
        const int ins_c = (Rc <= 0.0f) ? 1 : 0;
        const int ins_p = __shfl(ins_c, pidx);          // inside(prev) == ins_c at pidx

        const bool valid  = (lane < n);
        const bool emit_i = valid && ((ins_c ^ ins_p) != 0);
        const bool emit_c = valid && (ins_c != 0);

        // intersection of line(prev,cur) with line(c1,c2) — reference arithmetic
        const float dx12 = px - prx, dy12 = py - pry;
        const float dx34 = c2x - c1x;
        const float m1 = dy12 / safe_(dx12);
        const float b1 = pry - m1 * prx;
        const float m2 = (c2y - c1y) / safe_(dx34);
        const float b2 = c1y - m2 * c1x;
        const float xg = (b2 - b1) / safe_(m1 - m2);
        const float yg = m1 * xg + b1;
        float ix, iy;
        if (dx12 == 0.0f)      { ix = prx; iy = m2 * prx + b2; }   // vert1 wins
        else if (dx34 == 0.0f) { ix = c1x; iy = m1 * c1x + b1; }   // vert2
        else                   { ix = xg;  iy = yg; }

        // cumsum offsets via ballots (matches jnp.cumsum(cnt) - cnt)
        const unsigned long long bi = __ballot(emit_i ? 1 : 0);
        const unsigned long long bc = __ballot(emit_c ? 1 : 0);
        const unsigned long long lower = (1ull << lane) - 1ull;
        const int off   = __popcll(bi & lower) + __popcll(bc & lower);
        const int total = __popcll(bi) + __popcll(bc);

        __syncthreads();                                  // WAR vs previous gather
        if (emit_i) {
            const int p0 = off;                           // writes >= MAXN dumped
            if (p0 < MAXN) { bufx[wave][p0] = ix; bufy[wave][p0] = iy; }
        }
        if (emit_c) {
            const int p1 = off + (emit_i ? 1 : 0);
            if (p1 < MAXN) { bufx[wave][p1] = px; bufy[wave][p1] = py; }
        }
        __syncthreads();                                  // RAW: scatter -> gather

        n = (total < MAXN) ? total : MAXN;
        px = (lane < n) ? bufx[wave][lane] : 0.0f;        // ref buf is zero-filled
        py = (lane < n) ? bufy[wave][lane] : 0.0f;
    }

    // ---- _area_padded (with the reference's duplicated 0->1 edge term) ----
    auto area = [&](float x, float y, int nn) -> float {
        const int ns = (nn > 0) ? nn : 1;
        const int nxt = (lane + 1) % ns;
        const float xn = __shfl(x, nxt);
        const float yn = __shfl(y, nxt);
        const bool val = (lane < nn);
        float l = val ? x * yn : 0.0f;
        float r = val ? y * xn : 0.0f;
        #pragma unroll
        for (int o = 32; o > 0; o >>= 1) {
            l += __shfl_down(l, o);
            r += __shfl_down(r, o);
        }
        l = __shfl(l, 0);
        r = __shfl(r, 0);
        const int i1 = 1 % ns;
        const float x0 = __shfl(x, 0),  y0 = __shfl(y, 0);
        const float xi = __shfl(x, i1), yi = __shfl(y, i1);
        if (nn > 0) { l += x0 * yi; r += y0 * xi; }
        return fabsf(0.5f * (r - l));
    };

    const float a_i = area(px, py, n);
    const float a_p = area(sx, sy, V);
    const float a_g = area(cx, cy, V);

    const float inter = ((a_i == 0.0f) ? fminf(a_p, a_g) : 0.0f) + a_i;
    const float uni   = a_g + a_p - inter;
    const float iou   = inter / (uni + 1e-6f);

    if (live && lane == 0) {
        const float m = mask[pair];
        atomicAdd(&acc[0], iou * m);
        atomicAdd(&acc[1], m);
    }
}

__global__ void poly_finalize_kernel(const float* __restrict__ acc,
                                     float* __restrict__ out)
{
    out[0] = 1.0f - acc[0] / (acc[1] + 1e-6f);
}

extern "C" void kernel_launch(void* const* d_in, const int* in_sizes, int n_in,
                              void* d_out, int out_size, void* d_ws, size_t ws_size,
                              hipStream_t stream) {
    const float* output = (const float*)d_in[0];
    const float* mask   = (const float*)d_in[1];
    const int*   ind    = (const int*)d_in[2];
    const float* target = (const float*)d_in[3];
    float* out = (float*)d_out;
    float* acc = (float*)d_ws;

    const int BK = in_sizes[1];                 // B*K (mask elements)
    const int B  = 16;                          // per setup_inputs
    const int K  = BK / B;
    const int HW = in_sizes[0] / (B * 2 * V);   // 256*256

    hipMemsetAsync(acc, 0, 2 * sizeof(float), stream);

    const int pairs_per_block = WAVES_PER_BLOCK;
    const int grid = (BK + pairs_per_block - 1) / pairs_per_block;
    poly_iou_kernel<<<grid, 64 * WAVES_PER_BLOCK, 0, stream>>>(
        output, mask, ind, target, acc, BK, K, HW);
    poly_finalize_kernel<<<1, 1, 0, stream>>>(acc, out);
}

// Round 2
// 177.616 us; speedup vs baseline: 1.2645x; 1.2645x over previous
//
#include <hip/hip_runtime.h>

#define V 16
#define MAXN 64
#define WAVES_PER_BLOCK 4

__device__ __forceinline__ float safe_(float d) { return (d == 0.0f) ? 1.0f : d; }

// Wave-local LDS fence: all lanes of a wave execute in lockstep, so ordering
// LDS scatter -> gather within one wave only needs lgkmcnt(0) (no s_barrier).
__device__ __forceinline__ void wave_lds_fence() {
    __asm__ volatile("s_waitcnt lgkmcnt(0)" ::: "memory");
}

// One wave (64 lanes) per polygon pair. lane = vertex slot (MAXN==64).
__global__ __launch_bounds__(256) void poly_iou_kernel(
    const float* __restrict__ output,  // [B, 2V, HW]
    const float* __restrict__ mask,    // [B, K]
    const int*   __restrict__ ind,     // [B, K]
    const float* __restrict__ target,  // [B, K, 2V]
    float* __restrict__ iou_ws,        // [BK]: iou * mask per pair
    int BK, int K, int HW)
{
    __shared__ float bufx[WAVES_PER_BLOCK][MAXN];
    __shared__ float bufy[WAVES_PER_BLOCK][MAXN];

    const int lane = threadIdx.x & 63;
    const int wave = threadIdx.x >> 6;
    int pair = blockIdx.x * WAVES_PER_BLOCK + wave;
    const bool live = pair < BK;
    if (!live) pair = 0;                 // keep wave running (uniform control)
    const int b = pair / K;              // wave-uniform, once — cheap

    // ---- load subject (pred, gathered) and clip (target) polygons ----
    float px = 0.0f, py = 0.0f;          // working poly[lane]
    float sx = 0.0f, sy = 0.0f;          // subject copy (for a_p)
    float cx = 0.0f, cy = 0.0f;          // clip vertex   (for edges + a_g)
    if (lane < V) {
        const int idx = ind[pair];
        const float* ob = output + ((size_t)b * (2 * V)) * (size_t)HW;
        sx = ob[(size_t)(2 * lane) * HW + idx];
        sy = ob[(size_t)(2 * lane + 1) * HW + idx];
        const float2 t2 = ((const float2*)(target + (size_t)pair * (2 * V)))[lane];
        cx = t2.x;
        cy = t2.y;
        px = sx; py = sy;
    }
    int n = V;

    // ---- Sutherland–Hodgman clip: 16 edges (c1=clip[t-1], c2=clip[t]) ----
    for (int t = 0; t < V; ++t) {
        const int t1 = (t + V - 1) & (V - 1);
        const float c1x = __shfl(cx, t1), c1y = __shfl(cy, t1);
        const float c2x = __shfl(cx, t),  c2y = __shfl(cy, t);

        // prev index: (lane-1) mod n, but only lanes < n matter -> cndmask
        const int pidx = (lane == 0) ? (n - 1) : (lane - 1);
        const float prx = __shfl(px, pidx);
        const float pry = __shfl(py, pidx);

        // inside test: R = (c2x-c1x)*(qy-c1y) - (c2y-c1y)*(qx-c1x); inside = R<=0
        const float Rc = (c2x - c1x) * (py - c1y) - (c2y - c1y) * (px - c1x);
        const int ins_c = (Rc <= 0.0f) ? 1 : 0;
        const int ins_p = __shfl(ins_c, pidx);

        const bool valid  = (lane < n);
        const bool emit_i = valid && ((ins_c ^ ins_p) != 0);
        const bool emit_c = valid && (ins_c != 0);

        // intersection of line(prev,cur) with line(c1,c2) — reference arithmetic
        const float dx12 = px - prx, dy12 = py - pry;
        const float dx34 = c2x - c1x;
        const float m1 = dy12 / safe_(dx12);
        const float b1 = pry - m1 * prx;
        const float m2 = (c2y - c1y) / safe_(dx34);
        const float b2 = c1y - m2 * c1x;
        const float xg = (b2 - b1) / safe_(m1 - m2);
        const float yg = m1 * xg + b1;
        float ix, iy;
        if (dx12 == 0.0f)      { ix = prx; iy = m2 * prx + b2; }   // vert1 wins
        else if (dx34 == 0.0f) { ix = c1x; iy = m1 * c1x + b1; }   // vert2
        else                   { ix = xg;  iy = yg; }

        // cumsum offsets via ballots (matches jnp.cumsum(cnt) - cnt)
        const unsigned long long bi = __ballot(emit_i ? 1 : 0);
        const unsigned long long bc = __ballot(emit_c ? 1 : 0);
        const unsigned long long lower = (1ull << lane) - 1ull;
        const int off   = __popcll(bi & lower) + __popcll(bc & lower);
        const int total = __popcll(bi) + __popcll(bc);

        wave_lds_fence();                                 // WAR vs previous gather
        if (emit_i) {
            const int p0 = off;                           // writes >= MAXN dumped
            if (p0 < MAXN) { bufx[wave][p0] = ix; bufy[wave][p0] = iy; }
        }
        if (emit_c) {
            const int p1 = off + (emit_i ? 1 : 0);
            if (p1 < MAXN) { bufx[wave][p1] = px; bufy[wave][p1] = py; }
        }
        wave_lds_fence();                                 // RAW: scatter -> gather

        n = (total < MAXN) ? total : MAXN;
        px = (lane < n) ? bufx[wave][lane] : 0.0f;        // ref buf is zero-filled
        py = (lane < n) ? bufy[wave][lane] : 0.0f;
    }

    // ---- _area_padded (with the reference's duplicated 0->1 edge term) ----
    auto area = [&](float x, float y, int nn) -> float {
        const int ns = (nn > 0) ? nn : 1;
        const int nxt = (lane + 1 == ns) ? 0 : (lane + 1);    // (lane+1)%ns for lane<nn
        const float xn = __shfl(x, nxt);
        const float yn = __shfl(y, nxt);
        const bool val = (lane < nn);
        float l = val ? x * yn : 0.0f;
        float r = val ? y * xn : 0.0f;
        #pragma unroll
        for (int o = 32; o > 0; o >>= 1) {
            l += __shfl_xor(l, o);
            r += __shfl_xor(r, o);
        }
        const int i1 = (ns > 1) ? 1 : 0;
        const float x0 = __shfl(x, 0),  y0 = __shfl(y, 0);
        const float xi = __shfl(x, i1), yi = __shfl(y, i1);
        if (nn > 0) { l += x0 * yi; r += y0 * xi; }
        return fabsf(0.5f * (r - l));
    };

    const float a_i = area(px, py, n);
    const float a_p = area(sx, sy, V);
    const float a_g = area(cx, cy, V);

    const float inter = ((a_i == 0.0f) ? fminf(a_p, a_g) : 0.0f) + a_i;
    const float uni   = a_g + a_p - inter;
    const float iou   = inter / (uni + 1e-6f);

    if (live && lane == 0) {
        iou_ws[pair] = iou * mask[pair];                  // no atomics
    }
}

// Deterministic single-block reduction of iou*mask and mask sums.
__global__ __launch_bounds__(256) void poly_finalize_kernel(
    const float* __restrict__ iou_ws,
    const float* __restrict__ mask,
    float* __restrict__ out, int BK)
{
    float si = 0.0f, sm = 0.0f;
    for (int i = threadIdx.x; i < BK; i += 256) {
        si += iou_ws[i];
        sm += mask[i];
    }
    #pragma unroll
    for (int o = 32; o > 0; o >>= 1) {
        si += __shfl_xor(si, o);
        sm += __shfl_xor(sm, o);
    }
    __shared__ float a[4], c[4];
    const int wave = threadIdx.x >> 6;
    if ((threadIdx.x & 63) == 0) { a[wave] = si; c[wave] = sm; }
    __syncthreads();
    if (threadIdx.x == 0) {
        const float ti = a[0] + a[1] + a[2] + a[3];
        const float tm = c[0] + c[1] + c[2] + c[3];
        out[0] = 1.0f - ti / (tm + 1e-6f);
    }
}

extern "C" void kernel_launch(void* const* d_in, const int* in_sizes, int n_in,
                              void* d_out, int out_size, void* d_ws, size_t ws_size,
                              hipStream_t stream) {
    const float* output = (const float*)d_in[0];
    const float* mask   = (const float*)d_in[1];
    const int*   ind    = (const int*)d_in[2];
    const float* target = (const float*)d_in[3];
    float* out = (float*)d_out;
    float* iou_ws = (float*)d_ws;

    const int BK = in_sizes[1];                 // B*K (mask elements)
    const int B  = 16;                          // per setup_inputs
    const int K  = BK / B;
    const int HW = in_sizes[0] / (B * 2 * V);   // 256*256

    const int grid = (BK + WAVES_PER_BLOCK - 1) / WAVES_PER_BLOCK;
    poly_iou_kernel<<<grid, 64 * WAVES_PER_BLOCK, 0, stream>>>(
        output, mask, ind, target, iou_ws, BK, K, HW);
    poly_finalize_kernel<<<1, 256, 0, stream>>>(iou_ws, mask, out, BK);
}

// Round 3
// 176.165 us; speedup vs baseline: 1.2749x; 1.0082x over previous
//
#include <hip/hip_runtime.h>

#define V 16
#define MAXN 64
#define WAVES_PER_BLOCK 4

__device__ __forceinline__ float safe_(float d) { return (d == 0.0f) ? 1.0f : d; }

// popcount(m & ((1<<lane)-1)) in 2 instructions
__device__ __forceinline__ int lower_popcount(unsigned long long m) {
    return __builtin_amdgcn_mbcnt_hi((unsigned)(m >> 32),
           __builtin_amdgcn_mbcnt_lo((unsigned)m, 0));
}

// One wave (64 lanes) per polygon pair. lane = vertex slot (MAXN==64).
// NOTE: no explicit LDS fences — DS ops from a single wave are processed in
// program order by the LDS unit, so scatter(t) cannot pass gather(t-1), and
// the compiler inserts lgkmcnt for the ds_read register dependency.
__global__ __launch_bounds__(256) void poly_iou_kernel(
    const float* __restrict__ output,  // [B, 2V, HW]
    const float* __restrict__ mask,    // [B, K]
    const int*   __restrict__ ind,     // [B, K]
    const float* __restrict__ target,  // [B, K, 2V]
    float* __restrict__ iou_ws,        // [BK]: iou * mask per pair
    int BK, int K, int HW)
{
    __shared__ float bufx[WAVES_PER_BLOCK][MAXN];
    __shared__ float bufy[WAVES_PER_BLOCK][MAXN];

    const int lane = threadIdx.x & 63;
    const int wave = threadIdx.x >> 6;
    int pair = blockIdx.x * WAVES_PER_BLOCK + wave;
    const bool live = pair < BK;
    if (!live) pair = 0;                 // keep wave running (uniform control)
    const int b = pair / K;              // wave-uniform

    // ---- load subject (pred, gathered) and clip (target) polygons ----
    float px = 0.0f, py = 0.0f;          // working poly[lane]
    float sx = 0.0f, sy = 0.0f;          // subject copy (for a_p)
    float cx = 0.0f, cy = 0.0f;          // clip vertex   (for edges + a_g)
    if (lane < V) {
        const int idx = ind[pair];
        const float* ob = output + ((size_t)b * (2 * V)) * (size_t)HW;
        sx = ob[(size_t)(2 * lane) * HW + idx];
        sy = ob[(size_t)(2 * lane + 1) * HW + idx];
        const float2 t2 = ((const float2*)(target + (size_t)pair * (2 * V)))[lane];
        cx = t2.x;
        cy = t2.y;
        px = sx; py = sy;
    }
    int n = V;

    // ---- Sutherland–Hodgman clip: 16 edges (c1=clip[t-1], c2=clip[t]) ----
    for (int t = 0; t < V; ++t) {
        if (n == 0) break;               // wave-uniform: empty stays empty,
                                         // px/py already zero-filled

        const int t1 = (t + V - 1) & (V - 1);
        const float c1x = __shfl(cx, t1), c1y = __shfl(cy, t1);
        const float c2x = __shfl(cx, t),  c2y = __shfl(cy, t);

        // prev index: (lane-1) mod n; only lanes < n matter
        const int pidx = (lane == 0) ? (n - 1) : (lane - 1);
        const float prx = __shfl(px, pidx);
        const float pry = __shfl(py, pidx);

        // inside test: R = (c2x-c1x)*(qy-c1y) - (c2y-c1y)*(qx-c1x); inside = R<=0
        const float Rc = (c2x - c1x) * (py - c1y) - (c2y - c1y) * (px - c1x);
        const int ins_c = (Rc <= 0.0f) ? 1 : 0;
        const int ins_p = __shfl(ins_c, pidx);

        const bool valid  = (lane < n);
        const bool emit_i = valid && ((ins_c ^ ins_p) != 0);
        const bool emit_c = valid && (ins_c != 0);

        // intersection of line(prev,cur) with line(c1,c2) — reference arithmetic
        const float dx12 = px - prx, dy12 = py - pry;
        const float dx34 = c2x - c1x;
        const float m1 = dy12 / safe_(dx12);
        const float b1 = pry - m1 * prx;
        const float m2 = (c2y - c1y) / safe_(dx34);
        const float b2 = c1y - m2 * c1x;
        const float xg = (b2 - b1) / safe_(m1 - m2);
        const float yg = m1 * xg + b1;
        float ix, iy;
        if (dx12 == 0.0f)      { ix = prx; iy = m2 * prx + b2; }   // vert1 wins
        else if (dx34 == 0.0f) { ix = c1x; iy = m1 * c1x + b1; }   // vert2
        else                   { ix = xg;  iy = yg; }

        // cumsum offsets via ballots (matches jnp.cumsum(cnt) - cnt)
        const unsigned long long bi = __ballot(emit_i ? 1 : 0);
        const unsigned long long bc = __ballot(emit_c ? 1 : 0);
        const int off   = lower_popcount(bi) + lower_popcount(bc);
        const int total = __popcll(bi) + __popcll(bc);

        if (emit_i) {
            const int p0 = off;                           // writes >= MAXN dumped
            if (p0 < MAXN) { bufx[wave][p0] = ix; bufy[wave][p0] = iy; }
        }
        if (emit_c) {
            const int p1 = off + (emit_i ? 1 : 0);
            if (p1 < MAXN) { bufx[wave][p1] = px; bufy[wave][p1] = py; }
        }

        n = (total < MAXN) ? total : MAXN;
        px = (lane < n) ? bufx[wave][lane] : 0.0f;        // ref buf is zero-filled
        py = (lane < n) ? bufy[wave][lane] : 0.0f;
    }

    // ---- _area_padded (with the reference's duplicated 0->1 edge term) ----
    auto area = [&](float x, float y, int nn) -> float {
        const int ns = (nn > 0) ? nn : 1;
        const int nxt = (lane + 1 == ns) ? 0 : (lane + 1);
        const float xn = __shfl(x, nxt);
        const float yn = __shfl(y, nxt);
        const bool val = (lane < nn);
        float l = val ? x * yn : 0.0f;
        float r = val ? y * xn : 0.0f;
        #pragma unroll
        for (int o = 32; o > 0; o >>= 1) {
            l += __shfl_xor(l, o);
            r += __shfl_xor(r, o);
        }
        const int i1 = (ns > 1) ? 1 : 0;
        const float x0 = __shfl(x, 0),  y0 = __shfl(y, 0);
        const float xi = __shfl(x, i1), yi = __shfl(y, i1);
        if (nn > 0) { l += x0 * yi; r += y0 * xi; }
        return fabsf(0.5f * (r - l));
    };

    const float a_i = area(px, py, n);
    const float a_p = area(sx, sy, V);
    const float a_g = area(cx, cy, V);

    const float inter = ((a_i == 0.0f) ? fminf(a_p, a_g) : 0.0f) + a_i;
    const float uni   = a_g + a_p - inter;
    const float iou   = inter / (uni + 1e-6f);

    if (live && lane == 0) {
        iou_ws[pair] = iou * mask[pair];                  // no atomics
    }
}

// Deterministic single-block reduction of iou*mask and mask sums.
__global__ __launch_bounds__(256) void poly_finalize_kernel(
    const float* __restrict__ iou_ws,
    const float* __restrict__ mask,
    float* __restrict__ out, int BK)
{
    float si = 0.0f, sm = 0.0f;
    for (int i = threadIdx.x; i < BK; i += 256) {
        si += iou_ws[i];
        sm += mask[i];
    }
    #pragma unroll
    for (int o = 32; o > 0; o >>= 1) {
        si += __shfl_xor(si, o);
        sm += __shfl_xor(sm, o);
    }
    __shared__ float a[4], c[4];
    const int wave = threadIdx.x >> 6;
    if ((threadIdx.x & 63) == 0) { a[wave] = si; c[wave] = sm; }
    __syncthreads();
    if (threadIdx.x == 0) {
        const float ti = a[0] + a[1] + a[2] + a[3];
        const float tm = c[0] + c[1] + c[2] + c[3];
        out[0] = 1.0f - ti / (tm + 1e-6f);
    }
}

extern "C" void kernel_launch(void* const* d_in, const int* in_sizes, int n_in,
                              void* d_out, int out_size, void* d_ws, size_t ws_size,
                              hipStream_t stream) {
    const float* output = (const float*)d_in[0];
    const float* mask   = (const float*)d_in[1];
    const int*   ind    = (const int*)d_in[2];
    const float* target = (const float*)d_in[3];
    float* out = (float*)d_out;
    float* iou_ws = (float*)d_ws;

    const int BK = in_sizes[1];                 // B*K (mask elements)
    const int B  = 16;                          // per setup_inputs
    const int K  = BK / B;
    const int HW = in_sizes[0] / (B * 2 * V);   // 256*256

    const int grid = (BK + WAVES_PER_BLOCK - 1) / WAVES_PER_BLOCK;
    poly_iou_kernel<<<grid, 64 * WAVES_PER_BLOCK, 0, stream>>>(
        output, mask, ind, target, iou_ws, BK, K, HW);
    poly_finalize_kernel<<<1, 256, 0, stream>>>(iou_ws, mask, out, BK);
}